// Round 4
// baseline (241.560 us; speedup 1.0000x reference)
//
#include <hip/hip_runtime.h>
#include <hip/hip_bf16.h>

typedef __hip_bfloat16 bf16;
typedef __attribute__((ext_vector_type(8))) short s8v;   // 8 bf16 MFMA A/B frag
typedef __attribute__((ext_vector_type(4))) float f4v;   // MFMA C/D frag

#define D_MODEL 1024
#define S_LEN   2048
#define BATCH   2
#define NH      16
#define HD      64
#define M_TOTAL 4096
#define NT      (S_LEN / 64)

// ---- async global->LDS, 16B per lane; LDS dest = uniform base + lane*16 ----
__device__ __forceinline__ void gll16(const bf16* g, bf16* l) {
    __builtin_amdgcn_global_load_lds(
        (const __attribute__((address_space(1))) void*)g,
        (__attribute__((address_space(3))) void*)l, 16, 0, 0);
}

// ---------------- fp32 -> bf16 converts ----------------
__global__ __launch_bounds__(256) void cvt_bf16x8(const float* __restrict__ s,
                                                  bf16* __restrict__ d, int n) {
    int i = (blockIdx.x * 256 + threadIdx.x) * 8;
    if (i < n) {
        float4 a = *(const float4*)(s + i);
        float4 b = *(const float4*)(s + i + 4);
        union { bf16 h[8]; uint4 u; } p;
        p.h[0] = __float2bfloat16(a.x); p.h[1] = __float2bfloat16(a.y);
        p.h[2] = __float2bfloat16(a.z); p.h[3] = __float2bfloat16(a.w);
        p.h[4] = __float2bfloat16(b.x); p.h[5] = __float2bfloat16(b.y);
        p.h[6] = __float2bfloat16(b.z); p.h[7] = __float2bfloat16(b.w);
        *(uint4*)(d + i) = p.u;
    }
}

struct WPtrs { const float* s0; const float* s1; const float* s2; const float* s3;
               bf16* d0; bf16* d1; bf16* d2; bf16* d3; };

__global__ __launch_bounds__(256) void cvt_w(WPtrs p) {
    const float* s; bf16* d;
    switch (blockIdx.y) {
        case 0:  s = p.s0; d = p.d0; break;
        case 1:  s = p.s1; d = p.d1; break;
        case 2:  s = p.s2; d = p.d2; break;
        default: s = p.s3; d = p.d3; break;
    }
    int i = (blockIdx.x * 256 + threadIdx.x) * 8;
    float4 a = *(const float4*)(s + i);
    float4 b = *(const float4*)(s + i + 4);
    union { bf16 h[8]; uint4 u; } q;
    q.h[0] = __float2bfloat16(a.x); q.h[1] = __float2bfloat16(a.y);
    q.h[2] = __float2bfloat16(a.z); q.h[3] = __float2bfloat16(a.w);
    q.h[4] = __float2bfloat16(b.x); q.h[5] = __float2bfloat16(b.y);
    q.h[6] = __float2bfloat16(b.z); q.h[7] = __float2bfloat16(b.w);
    *(uint4*)(d + i) = q.u;
}

// ---------------- GEMM main loop: 2-phase double-buffered ----------------
// C[M,N] = A[M,K=1024] @ W[N,K]^T. BK=32, 4 waves 2x2. LDS [2][rows][32] bf16,
// staged via global_load_lds w=16. One barrier per K-step; next-tile loads get
// the full compute phase to land (drained by __syncthreads' implicit vmcnt(0)).
template<int TM, int TN>
__device__ __forceinline__ void gemm_main(const bf16* __restrict__ A,
                                          const bf16* __restrict__ W,
                                          bf16* As, bf16* Bs,     // each [2][T*32]
                                          int bm, int bn,
                                          f4v (&acc)[TM/32][TN/32])
{
    constexpr int FM = TM / 32, FN = TN / 32;
    constexpr int CALLS_A = TM / 16, CALLS = (TM + TN) / 16, PW = CALLS / 4;
    const int t = threadIdx.x, wv = t >> 6, lane = t & 63;
    const int quad = lane >> 4, l15 = lane & 15;
    const int wm = (wv >> 1) * (TM / 2), wn = (wv & 1) * (TN / 2);
    const int lr = lane >> 2, lc = (lane & 3) * 8;

    auto STAGE = [&](int buf, int k0) {
        #pragma unroll
        for (int c = 0; c < PW; ++c) {
            const int cc = wv * PW + c;
            if (cc < CALLS_A) {
                gll16(A + (size_t)(bm + cc * 16 + lr) * D_MODEL + k0 + lc,
                      As + buf * (TM * 32) + cc * 16 * 32);
            } else {
                const int r2 = cc - CALLS_A;
                gll16(W + (size_t)(bn + r2 * 16 + lr) * D_MODEL + k0 + lc,
                      Bs + buf * (TN * 32) + r2 * 16 * 32);
            }
        }
    };

    STAGE(0, 0);
    __syncthreads();
    int cur = 0;

    for (int k0 = 0; k0 < D_MODEL; k0 += 32) {
        if (k0 + 32 < D_MODEL) STAGE(cur ^ 1, k0 + 32);

        const bf16* ab = As + cur * (TM * 32);
        const bf16* bb = Bs + cur * (TN * 32);
        s8v af[FM], bfv[FN];
        #pragma unroll
        for (int i = 0; i < FM; ++i)
            af[i] = *(const s8v*)(ab + (wm + i * 16 + l15) * 32 + quad * 8);
        #pragma unroll
        for (int j = 0; j < FN; ++j)
            bfv[j] = *(const s8v*)(bb + (wn + j * 16 + l15) * 32 + quad * 8);
        __builtin_amdgcn_s_setprio(1);
        #pragma unroll
        for (int i = 0; i < FM; ++i)
            #pragma unroll
            for (int j = 0; j < FN; ++j)
                acc[i][j] = __builtin_amdgcn_mfma_f32_16x16x32_bf16(af[i], bfv[j], acc[i][j], 0, 0, 0);
        __builtin_amdgcn_s_setprio(0);

        __syncthreads();      // drains this wave's gll16 (vmcnt) + frag reads (lgkm)
        cur ^= 1;
    }
}

// Fused QKV: grid (8, 32, 3); z=0 Q, z=1 K ([b][h][s][d]); z=2 V^T ([b][h][d][s]).
// Tw overlays the double-buffered As/Bs (epilogue-only use).
__global__ __launch_bounds__(256) void gemm_qkv(
    const bf16* __restrict__ x,
    const bf16* __restrict__ Wq, const bf16* __restrict__ Wk, const bf16* __restrict__ Wv,
    const float* __restrict__ bq, const float* __restrict__ bk, const float* __restrict__ bv,
    bf16* __restrict__ Qb, bf16* __restrict__ Kb, bf16* __restrict__ Vtb)
{
    __shared__ __align__(16) char smem[4 * 64 * 72 * 2];   // 36864 B >= dbuf As+Bs (32768 B)
    bf16* As = (bf16*)smem;                                 // [2][128*32]
    bf16* Bs = (bf16*)(smem + 2 * 128 * 32 * 2);            // [2][128*32]
    bf16 (*Tw)[64][72] = (bf16(*)[64][72])smem;             // z==2 transpose staging

    const int z = blockIdx.z;
    const bf16*  W    = (z == 0) ? Wq : (z == 1) ? Wk : Wv;
    const float* bias = (z == 0) ? bq : (z == 1) ? bk : bv;
    bf16*        out  = (z == 0) ? Qb : (z == 1) ? Kb : Vtb;
    const int bm = blockIdx.y * 128, bn = blockIdx.x * 128;

    f4v acc[4][4] = {};
    gemm_main<128, 128>(x, W, As, Bs, bm, bn, acc);

    const int t = threadIdx.x, wv = t >> 6, lane = t & 63;
    const int quad = lane >> 4, l15 = lane & 15;
    const int wm = (wv >> 1) * 64, wn = (wv & 1) * 64;

    if (z == 2) {
        __syncthreads();   // all waves done with As/Bs before Tw overwrites them
        #pragma unroll
        for (int j = 0; j < 4; ++j) {
            const int col = bn + wn + j * 16 + l15;
            const float bv_ = bias[col];
            #pragma unroll
            for (int i = 0; i < 4; ++i) {
                #pragma unroll
                for (int rp = 0; rp < 4; rp += 2) {
                    union { bf16 h[2]; unsigned u; } p2;
                    p2.h[0] = __float2bfloat16(acc[i][j][rp]     + bv_);
                    p2.h[1] = __float2bfloat16(acc[i][j][rp + 1] + bv_);
                    *(unsigned*)&Tw[wv][j * 16 + l15][i * 16 + quad * 4 + rp] = p2.u;
                }
            }
        }
        // wave-local round-trip: compiler inserts lgkmcnt wait, no barrier needed
        const int bb = (bm + wm) >> 11, s0 = (bm + wm) & 2047;
        #pragma unroll
        for (int p = 0; p < 8; ++p) {
            const int dl = p * 8 + (lane >> 3);
            const int sl = (lane & 7) * 8;
            const int col = bn + wn + dl;
            const int h = col >> 6, d = col & 63;
            uint4 v = *(const uint4*)&Tw[wv][dl][sl];
            *(uint4*)&out[(((size_t)(bb * NH + h)) * HD + d) * S_LEN + s0 + sl] = v;
        }
    } else {
        #pragma unroll
        for (int j = 0; j < 4; ++j) {
            const int col = bn + wn + j * 16 + l15;
            const float bv_ = bias[col];
            const int h = col >> 6, d = col & 63;
            #pragma unroll
            for (int i = 0; i < 4; ++i) {
                #pragma unroll
                for (int r = 0; r < 4; ++r) {
                    const int row = bm + wm + i * 16 + quad * 4 + r;
                    const int b = row >> 11, s = row & 2047;
                    const float v = acc[i][j][r] + bv_;
                    out[(((size_t)(b * NH + h)) * S_LEN + s) * HD + d] = __float2bfloat16(v);
                }
            }
        }
    }
}

// Output projection: 64x128 tiles -> grid (8, 64) = 512 blocks. fp32 out.
__global__ __launch_bounds__(256) void gemm_out(
    const bf16* __restrict__ Ob, const bf16* __restrict__ Wo,
    const float* __restrict__ bo, float* __restrict__ out)
{
    __shared__ __align__(16) bf16 As[2][64 * 32];
    __shared__ __align__(16) bf16 Bs[2][128 * 32];
    const int bm = blockIdx.y * 64, bn = blockIdx.x * 128;

    f4v acc[2][4] = {};
    gemm_main<64, 128>(Ob, Wo, &As[0][0], &Bs[0][0], bm, bn, acc);

    const int t = threadIdx.x, wv = t >> 6, lane = t & 63;
    const int quad = lane >> 4, l15 = lane & 15;
    const int wm = (wv >> 1) * 32, wn = (wv & 1) * 64;
    #pragma unroll
    for (int j = 0; j < 4; ++j) {
        const int col = bn + wn + j * 16 + l15;
        const float bv_ = bo[col];
        #pragma unroll
        for (int i = 0; i < 2; ++i)
            #pragma unroll
            for (int r = 0; r < 4; ++r) {
                const int row = bm + wm + i * 16 + quad * 4 + r;
                out[(size_t)row * D_MODEL + col] = acc[i][j][r] + bv_;
            }
    }
}

// ---------------- Flash attention: 2-phase gll16 double-buffer ----------------
// S^T = K Q^T: lane (quad,l15) owns q=l15, k=c*16+quad*4+r.
// K/V staged direct-to-LDS via global_load_lds into [2][64][64] linear tiles
// with pre-swizzled GLOBAL source (chunk ^= row&7) + swizzled reads (rule #21).
// One __syncthreads per k-tile (implicit vmcnt(0) drains next-tile loads, which
// had the whole compute phase to land). Ps round-trip kept (verified), swizzled.
// LDS = 16384+16384+8192 = 40960 B exactly -> 4 blocks/CU.
__global__ __launch_bounds__(256) void attn_mfma(
    const bf16* __restrict__ Q, const bf16* __restrict__ K,
    const bf16* __restrict__ Vt, const int* __restrict__ mask,
    bf16* __restrict__ O)
{
    __shared__ __align__(16) bf16 Ks[2][64][64];
    __shared__ __align__(16) bf16 Vts[2][64][64];
    __shared__ __align__(16) bf16 Ps[4][16][64];   // per-wave P round-trip, swizzled

    const int t = threadIdx.x, wv = t >> 6, lane = t & 63;
    const int quad = lane >> 4, l15 = lane & 15;
    const int sw = l15 & 7;
    const int bid = blockIdx.x;
    const int b = bid & 1, h = (bid >> 1) & 15, qt = bid >> 5;   // (b,h) XCD-local
    const int q0 = qt * 64;
    const size_t qkbase = ((size_t)(b * NH + h)) * S_LEN * HD;
    const size_t vtbase = ((size_t)(b * NH + h)) * HD * S_LEN;

    const float KSC  = 0.125f * 1.44269504f;   // scale * log2(e)
    const float THR2 = 8.0f * 1.44269504f;     // defer-max threshold (log2 domain)

    // Q fragments (loop-invariant), straight from global
    const bf16* qrow = Q + qkbase + (size_t)(q0 + wv * 16 + l15) * HD;
    const s8v qf0 = *(const s8v*)(qrow + quad * 8);
    const s8v qf1 = *(const s8v*)(qrow + 32 + quad * 8);

    // gll16 staging: per wave 2 K-groups + 2 V-groups of 8 rows (1024 B each).
    // lane l -> row grl=l>>3, LDS chunk l&7; source chunk (l&7)^grl so that
    // LDS[r][c'] = G[r][c'^(r&7)].
    const int grl = lane >> 3, gch = (lane & 7) ^ grl;
    auto STAGEKV = [&](int bf, int kt2) {
        const int k0s = kt2 * 64;
        #pragma unroll
        for (int g = 0; g < 2; ++g) {
            const int r0 = wv * 16 + g * 8;
            gll16(K  + qkbase + (size_t)(k0s + r0 + grl) * HD + gch * 8,
                  &Ks[bf][r0][0]);
            gll16(Vt + vtbase + (size_t)(r0 + grl) * S_LEN + k0s + gch * 8,
                  &Vts[bf][r0][0]);
        }
    };

    STAGEKV(0, 0);
    __syncthreads();

    float mprev = -1e30f, lsum = 0.f;   // per-lane state for q = l15 (lsum partial)
    f4v oacc[4] = {};
    int cur = 0;

    for (int kt = 0; kt < NT; ++kt) {
        const int k0 = kt * 64;
        const bool more = (kt + 1 < NT);
        if (more) STAGEKV(cur ^ 1, kt + 1);   // full compute phase to land

        // mask words for this lane's 16 k-values (L1-resident, issued early)
        int4 mk[4];
        #pragma unroll
        for (int c = 0; c < 4; ++c)
            mk[c] = *(const int4*)&mask[b * S_LEN + k0 + c * 16 + quad * 4];

        const char* kbase = (const char*)&Ks[cur][0][0];
        const char* vbase = (const char*)&Vts[cur][0][0];

        // ---- S^T tiles: rows = k-local, cols = q (swizzled reads) ----
        f4v st[4];
        __builtin_amdgcn_s_setprio(1);
        #pragma unroll
        for (int c = 0; c < 4; ++c) {
            const char* kr = kbase + (c * 16 + l15) * 128;
            s8v kf0 = *(const s8v*)(kr + ((quad ^ sw) << 4));
            s8v kf1 = *(const s8v*)(kr + (((4 + quad) ^ sw) << 4));
            f4v z = {0.f, 0.f, 0.f, 0.f};
            z = __builtin_amdgcn_mfma_f32_16x16x32_bf16(kf0, qf0, z, 0, 0, 0);
            z = __builtin_amdgcn_mfma_f32_16x16x32_bf16(kf1, qf1, z, 0, 0, 0);
            st[c] = z;
        }
        __builtin_amdgcn_s_setprio(0);

        // ---- scale + mask bias (log2 domain); running max ----
        float mt = -1e30f;
        #pragma unroll
        for (int c = 0; c < 4; ++c) {
            f4v m4;
            m4[0] = mk[c].x ? 0.f : -1e30f;
            m4[1] = mk[c].y ? 0.f : -1e30f;
            m4[2] = mk[c].z ? 0.f : -1e30f;
            m4[3] = mk[c].w ? 0.f : -1e30f;
            st[c] = st[c] * KSC + m4;
            mt = fmaxf(mt, fmaxf(fmaxf(st[c][0], st[c][1]), fmaxf(st[c][2], st[c][3])));
        }
        mt = fmaxf(mt, __shfl_xor(mt, 16, 64));   // cross-quad: full 64-k max
        mt = fmaxf(mt, __shfl_xor(mt, 32, 64));

        // ---- defer-max rescale ----
        float mn = mprev;
        if (!__all(mt <= mprev + THR2)) {
            mn = fmaxf(mprev, mt);
            const float alpha = __builtin_amdgcn_exp2f(mprev - mn);
            mprev = mn;
            float av[4];
            #pragma unroll
            for (int r = 0; r < 4; ++r) av[r] = __shfl(alpha, quad * 4 + r, 64);
            #pragma unroll
            for (int dt = 0; dt < 4; ++dt)
                #pragma unroll
                for (int r = 0; r < 4; ++r) oacc[dt][r] *= av[r];
            lsum *= alpha;
        }

        f4v psv = {0.f, 0.f, 0.f, 0.f};
        #pragma unroll
        for (int c = 0; c < 4; ++c) {
            f4v e = st[c] - mn;
            e[0] = __builtin_amdgcn_exp2f(e[0]);
            e[1] = __builtin_amdgcn_exp2f(e[1]);
            e[2] = __builtin_amdgcn_exp2f(e[2]);
            e[3] = __builtin_amdgcn_exp2f(e[3]);
            st[c] = e;
            psv += e;
        }
        lsum += psv[0] + psv[1] + psv[2] + psv[3];

        // ---- P -> LDS [q][k] per-wave (swizzled b64 writes), read back as A-frag ----
        char* pr = (char*)&Ps[wv][l15][0];
        #pragma unroll
        for (int c = 0; c < 4; ++c) {
            union { bf16 hh[4]; short4 s4; } pk;
            pk.hh[0] = __float2bfloat16(st[c][0]);
            pk.hh[1] = __float2bfloat16(st[c][1]);
            pk.hh[2] = __float2bfloat16(st[c][2]);
            pk.hh[3] = __float2bfloat16(st[c][3]);
            const int wch = (2 * c + (quad >> 1)) ^ sw;
            *(short4*)(pr + (wch << 4) + ((quad & 1) << 3)) = pk.s4;
        }
        s8v pf0 = *(const s8v*)(pr + ((quad ^ sw) << 4));
        s8v pf1 = *(const s8v*)(pr + (((4 + quad) ^ sw) << 4));

        // ---- O += P V ----
        __builtin_amdgcn_s_setprio(1);
        #pragma unroll
        for (int dt = 0; dt < 4; ++dt) {
            const char* vr = vbase + (dt * 16 + l15) * 128;
            s8v vf0 = *(const s8v*)(vr + ((quad ^ sw) << 4));
            s8v vf1 = *(const s8v*)(vr + (((4 + quad) ^ sw) << 4));
            oacc[dt] = __builtin_amdgcn_mfma_f32_16x16x32_bf16(pf0, vf0, oacc[dt], 0, 0, 0);
            oacc[dt] = __builtin_amdgcn_mfma_f32_16x16x32_bf16(pf1, vf1, oacc[dt], 0, 0, 0);
        }
        __builtin_amdgcn_s_setprio(0);

        if (more) __syncthreads();    // vmcnt(0): next tile staged; lgkm: reads done
        cur ^= 1;
    }

    // ---- epilogue: finish lsum reduction, then O[b][s][h*64+d] ----
    lsum += __shfl_xor(lsum, 16, 64);
    lsum += __shfl_xor(lsum, 32, 64);
    float linv[4];
    #pragma unroll
    for (int r = 0; r < 4; ++r) linv[r] = 1.f / __shfl(lsum, quad * 4 + r, 64);
    #pragma unroll
    for (int dt = 0; dt < 4; ++dt) {
        #pragma unroll
        for (int r = 0; r < 4; ++r) {
            const int s = q0 + wv * 16 + quad * 4 + r;
            const int col = h * 64 + dt * 16 + l15;
            O[((size_t)b * S_LEN + s) * D_MODEL + col] = __float2bfloat16(oacc[dt][r] * linv[r]);
        }
    }
}

extern "C" void kernel_launch(void* const* d_in, const int* in_sizes, int n_in,
                              void* d_out, int out_size, void* d_ws, size_t ws_size,
                              hipStream_t stream) {
    const float* x    = (const float*)d_in[0];
    const int*   mask = (const int*)  d_in[1];
    const float* Wq   = (const float*)d_in[2];
    const float* bq   = (const float*)d_in[3];
    const float* Wk   = (const float*)d_in[4];
    const float* bk   = (const float*)d_in[5];
    const float* Wv   = (const float*)d_in[6];
    const float* bv   = (const float*)d_in[7];
    const float* Wo   = (const float*)d_in[8];
    const float* bo   = (const float*)d_in[9];
    float* out = (float*)d_out;

    char* w = (char*)d_ws;
    bf16* xb  = (bf16*)w; w += (size_t)M_TOTAL * D_MODEL * 2;
    bf16* Wqb = (bf16*)w; w += (size_t)D_MODEL * D_MODEL * 2;
    bf16* Wkb = (bf16*)w; w += (size_t)D_MODEL * D_MODEL * 2;
    bf16* Wvb = (bf16*)w; w += (size_t)D_MODEL * D_MODEL * 2;
    bf16* Wob = (bf16*)w; w += (size_t)D_MODEL * D_MODEL * 2;
    bf16* Qb  = (bf16*)w; w += (size_t)M_TOTAL * D_MODEL * 2;   // [b][h][s][d]
    bf16* Kb  = (bf16*)w; w += (size_t)M_TOTAL * D_MODEL * 2;   // [b][h][s][d]
    bf16* Vtb = (bf16*)w; w += (size_t)M_TOTAL * D_MODEL * 2;   // [b][h][d][s]
    bf16* Ob  = (bf16*)w; w += (size_t)M_TOTAL * D_MODEL * 2;   // [b][s][1024]

    const int nx = M_TOTAL * D_MODEL;
    cvt_bf16x8<<<nx / 2048, 256, 0, stream>>>(x, xb, nx);
    WPtrs wp = { Wq, Wk, Wv, Wo, Wqb, Wkb, Wvb, Wob };
    cvt_w<<<dim3(D_MODEL * D_MODEL / 2048, 4), 256, 0, stream>>>(wp);

    gemm_qkv<<<dim3(8, 32, 3), 256, 0, stream>>>(xb, Wqb, Wkb, Wvb, bq, bk, bv, Qb, Kb, Vtb);

    attn_mfma<<<BATCH * NH * (S_LEN / 64), 256, 0, stream>>>(Qb, Kb, Vtb, mask, Ob);

    gemm_out<<<dim3(8, 64), 256, 0, stream>>>(Ob, Wob, bo, out);
}

// Round 5
// 222.373 us; speedup vs baseline: 1.0863x; 1.0863x over previous
//
#include <hip/hip_runtime.h>
#include <hip/hip_bf16.h>

typedef __hip_bfloat16 bf16;
typedef __attribute__((ext_vector_type(8))) short s8v;   // 8 bf16 MFMA A/B frag
typedef __attribute__((ext_vector_type(4))) float f4v;   // MFMA C/D frag

#define D_MODEL 1024
#define S_LEN   2048
#define BATCH   2
#define NH      16
#define HD      64
#define M_TOTAL 4096
#define NT      (S_LEN / 64)

// ---- async global->LDS, 16B per lane; LDS dest = uniform base + lane*16 ----
__device__ __forceinline__ void gll16(const bf16* g, bf16* l) {
    __builtin_amdgcn_global_load_lds(
        (const __attribute__((address_space(1))) void*)g,
        (__attribute__((address_space(3))) void*)l, 16, 0, 0);
}

// ---------------- fp32 -> bf16 converts ----------------
__global__ __launch_bounds__(256) void cvt_bf16x8(const float* __restrict__ s,
                                                  bf16* __restrict__ d, int n) {
    int i = (blockIdx.x * 256 + threadIdx.x) * 8;
    if (i < n) {
        float4 a = *(const float4*)(s + i);
        float4 b = *(const float4*)(s + i + 4);
        union { bf16 h[8]; uint4 u; } p;
        p.h[0] = __float2bfloat16(a.x); p.h[1] = __float2bfloat16(a.y);
        p.h[2] = __float2bfloat16(a.z); p.h[3] = __float2bfloat16(a.w);
        p.h[4] = __float2bfloat16(b.x); p.h[5] = __float2bfloat16(b.y);
        p.h[6] = __float2bfloat16(b.z); p.h[7] = __float2bfloat16(b.w);
        *(uint4*)(d + i) = p.u;
    }
}

struct WPtrs { const float* s0; const float* s1; const float* s2; const float* s3;
               bf16* d0; bf16* d1; bf16* d2; bf16* d3; };

__global__ __launch_bounds__(256) void cvt_w(WPtrs p) {
    const float* s; bf16* d;
    switch (blockIdx.y) {
        case 0:  s = p.s0; d = p.d0; break;
        case 1:  s = p.s1; d = p.d1; break;
        case 2:  s = p.s2; d = p.d2; break;
        default: s = p.s3; d = p.d3; break;
    }
    int i = (blockIdx.x * 256 + threadIdx.x) * 8;
    float4 a = *(const float4*)(s + i);
    float4 b = *(const float4*)(s + i + 4);
    union { bf16 h[8]; uint4 u; } q;
    q.h[0] = __float2bfloat16(a.x); q.h[1] = __float2bfloat16(a.y);
    q.h[2] = __float2bfloat16(a.z); q.h[3] = __float2bfloat16(a.w);
    q.h[4] = __float2bfloat16(b.x); q.h[5] = __float2bfloat16(b.y);
    q.h[6] = __float2bfloat16(b.z); q.h[7] = __float2bfloat16(b.w);
    *(uint4*)(d + i) = q.u;
}

// ---------------- GEMM main loop: 2-phase double-buffered ----------------
// C[M,N] = A[M,K=1024] @ W[N,K]^T. BK=32, 4 waves 2x2. LDS [2][rows][32] bf16,
// staged via global_load_lds w=16. One barrier per K-step; next-tile loads get
// the full compute phase to land (drained by __syncthreads' implicit vmcnt(0)).
template<int TM, int TN>
__device__ __forceinline__ void gemm_main(const bf16* __restrict__ A,
                                          const bf16* __restrict__ W,
                                          bf16* As, bf16* Bs,     // each [2][T*32]
                                          int bm, int bn,
                                          f4v (&acc)[TM/32][TN/32])
{
    constexpr int FM = TM / 32, FN = TN / 32;
    constexpr int CALLS_A = TM / 16, CALLS = (TM + TN) / 16, PW = CALLS / 4;
    const int t = threadIdx.x, wv = t >> 6, lane = t & 63;
    const int quad = lane >> 4, l15 = lane & 15;
    const int wm = (wv >> 1) * (TM / 2), wn = (wv & 1) * (TN / 2);
    const int lr = lane >> 2, lc = (lane & 3) * 8;

    auto STAGE = [&](int buf, int k0) {
        #pragma unroll
        for (int c = 0; c < PW; ++c) {
            const int cc = wv * PW + c;
            if (cc < CALLS_A) {
                gll16(A + (size_t)(bm + cc * 16 + lr) * D_MODEL + k0 + lc,
                      As + buf * (TM * 32) + cc * 16 * 32);
            } else {
                const int r2 = cc - CALLS_A;
                gll16(W + (size_t)(bn + r2 * 16 + lr) * D_MODEL + k0 + lc,
                      Bs + buf * (TN * 32) + r2 * 16 * 32);
            }
        }
    };

    STAGE(0, 0);
    __syncthreads();
    int cur = 0;

    for (int k0 = 0; k0 < D_MODEL; k0 += 32) {
        if (k0 + 32 < D_MODEL) STAGE(cur ^ 1, k0 + 32);

        const bf16* ab = As + cur * (TM * 32);
        const bf16* bb = Bs + cur * (TN * 32);
        s8v af[FM], bfv[FN];
        #pragma unroll
        for (int i = 0; i < FM; ++i)
            af[i] = *(const s8v*)(ab + (wm + i * 16 + l15) * 32 + quad * 8);
        #pragma unroll
        for (int j = 0; j < FN; ++j)
            bfv[j] = *(const s8v*)(bb + (wn + j * 16 + l15) * 32 + quad * 8);
        __builtin_amdgcn_s_setprio(1);
        #pragma unroll
        for (int i = 0; i < FM; ++i)
            #pragma unroll
            for (int j = 0; j < FN; ++j)
                acc[i][j] = __builtin_amdgcn_mfma_f32_16x16x32_bf16(af[i], bfv[j], acc[i][j], 0, 0, 0);
        __builtin_amdgcn_s_setprio(0);

        __syncthreads();      // drains this wave's gll16 (vmcnt) + frag reads (lgkm)
        cur ^= 1;
    }
}

// Fused QKV: grid (8, 32, 3); z=0 Q, z=1 K ([b][h][s][d]); z=2 V^T ([b][h][d][s]).
// Tw overlays the double-buffered As/Bs (epilogue-only use).
__global__ __launch_bounds__(256) void gemm_qkv(
    const bf16* __restrict__ x,
    const bf16* __restrict__ Wq, const bf16* __restrict__ Wk, const bf16* __restrict__ Wv,
    const float* __restrict__ bq, const float* __restrict__ bk, const float* __restrict__ bv,
    bf16* __restrict__ Qb, bf16* __restrict__ Kb, bf16* __restrict__ Vtb)
{
    __shared__ __align__(16) char smem[4 * 64 * 72 * 2];   // 36864 B >= dbuf As+Bs (32768 B)
    bf16* As = (bf16*)smem;                                 // [2][128*32]
    bf16* Bs = (bf16*)(smem + 2 * 128 * 32 * 2);            // [2][128*32]
    bf16 (*Tw)[64][72] = (bf16(*)[64][72])smem;             // z==2 transpose staging

    const int z = blockIdx.z;
    const bf16*  W    = (z == 0) ? Wq : (z == 1) ? Wk : Wv;
    const float* bias = (z == 0) ? bq : (z == 1) ? bk : bv;
    bf16*        out  = (z == 0) ? Qb : (z == 1) ? Kb : Vtb;
    const int bm = blockIdx.y * 128, bn = blockIdx.x * 128;

    f4v acc[4][4] = {};
    gemm_main<128, 128>(x, W, As, Bs, bm, bn, acc);

    const int t = threadIdx.x, wv = t >> 6, lane = t & 63;
    const int quad = lane >> 4, l15 = lane & 15;
    const int wm = (wv >> 1) * 64, wn = (wv & 1) * 64;

    if (z == 2) {
        __syncthreads();   // all waves done with As/Bs before Tw overwrites them
        #pragma unroll
        for (int j = 0; j < 4; ++j) {
            const int col = bn + wn + j * 16 + l15;
            const float bv_ = bias[col];
            #pragma unroll
            for (int i = 0; i < 4; ++i) {
                #pragma unroll
                for (int rp = 0; rp < 4; rp += 2) {
                    union { bf16 h[2]; unsigned u; } p2;
                    p2.h[0] = __float2bfloat16(acc[i][j][rp]     + bv_);
                    p2.h[1] = __float2bfloat16(acc[i][j][rp + 1] + bv_);
                    *(unsigned*)&Tw[wv][j * 16 + l15][i * 16 + quad * 4 + rp] = p2.u;
                }
            }
        }
        // wave-local round-trip: compiler inserts lgkmcnt wait, no barrier needed
        const int bb = (bm + wm) >> 11, s0 = (bm + wm) & 2047;
        #pragma unroll
        for (int p = 0; p < 8; ++p) {
            const int dl = p * 8 + (lane >> 3);
            const int sl = (lane & 7) * 8;
            const int col = bn + wn + dl;
            const int h = col >> 6, d = col & 63;
            uint4 v = *(const uint4*)&Tw[wv][dl][sl];
            *(uint4*)&out[(((size_t)(bb * NH + h)) * HD + d) * S_LEN + s0 + sl] = v;
        }
    } else {
        #pragma unroll
        for (int j = 0; j < 4; ++j) {
            const int col = bn + wn + j * 16 + l15;
            const float bv_ = bias[col];
            const int h = col >> 6, d = col & 63;
            #pragma unroll
            for (int i = 0; i < 4; ++i) {
                #pragma unroll
                for (int r = 0; r < 4; ++r) {
                    const int row = bm + wm + i * 16 + quad * 4 + r;
                    const int b = row >> 11, s = row & 2047;
                    const float v = acc[i][j][r] + bv_;
                    out[(((size_t)(b * NH + h)) * S_LEN + s) * HD + d] = __float2bfloat16(v);
                }
            }
        }
    }
}

// Output projection: 64x128 tiles -> grid (8, 64) = 512 blocks. fp32 out.
__global__ __launch_bounds__(256) void gemm_out(
    const bf16* __restrict__ Ob, const bf16* __restrict__ Wo,
    const float* __restrict__ bo, float* __restrict__ out)
{
    __shared__ __align__(16) bf16 As[2][64 * 32];
    __shared__ __align__(16) bf16 Bs[2][128 * 32];
    const int bm = blockIdx.y * 64, bn = blockIdx.x * 128;

    f4v acc[2][4] = {};
    gemm_main<64, 128>(Ob, Wo, &As[0][0], &Bs[0][0], bm, bn, acc);

    const int t = threadIdx.x, wv = t >> 6, lane = t & 63;
    const int quad = lane >> 4, l15 = lane & 15;
    const int wm = (wv >> 1) * 32, wn = (wv & 1) * 64;
    #pragma unroll
    for (int j = 0; j < 4; ++j) {
        const int col = bn + wn + j * 16 + l15;
        const float bv_ = bo[col];
        #pragma unroll
        for (int i = 0; i < 2; ++i)
            #pragma unroll
            for (int r = 0; r < 4; ++r) {
                const int row = bm + wm + i * 16 + quad * 4 + r;
                out[(size_t)row * D_MODEL + col] = acc[i][j][r] + bv_;
            }
    }
}

// ---------------- Flash attention: round-1 structure + swizzled LDS ----------------
// S^T = K Q^T: lane (quad,l15) owns q=l15, k=c*16+quad*4+r.
// Reg-prefetch (LOADT kt+1 issued after barriers, consumed next iter's STAGE);
// single-buffered K/V, two barriers/iter (measured-best structure, 82.4 us).
// LDS unpadded [64][64] with both-sides XOR chunk-swizzle (chunk ^= row&7):
// reg-staged ds_writes pre-swizzle, reads apply same involution. Verified
// correct on-device in round 4; kills the ~4-way conflicts of the padded form.
// Block decode keeps all q-tiles of one (b,h) on one XCD (FETCH 69.7->12.4 MB).
// LDS = 8K(K)+8K(V)+8K(Ps)+256(mb) = 24832 B.
__global__ __launch_bounds__(256) void attn_mfma(
    const bf16* __restrict__ Q, const bf16* __restrict__ K,
    const bf16* __restrict__ Vt, const int* __restrict__ mask,
    bf16* __restrict__ O)
{
    __shared__ __align__(16) bf16 Ks[64][64];
    __shared__ __align__(16) bf16 Vts[64][64];
    __shared__ __align__(16) bf16 Ps[4][16][64];   // per-wave P round-trip, swizzled
    __shared__ float mb[64];                        // additive mask bias (log2 domain)

    const int t = threadIdx.x, wv = t >> 6, lane = t & 63;
    const int quad = lane >> 4, l15 = lane & 15;
    const int sw = l15 & 7;
    const int bid = blockIdx.x;
    const int b = bid & 1, h = (bid >> 1) & 15, qt = bid >> 5;   // (b,h) XCD-local
    const int q0 = qt * 64;
    const size_t qkbase = ((size_t)(b * NH + h)) * S_LEN * HD;
    const size_t vtbase = ((size_t)(b * NH + h)) * HD * S_LEN;

    const float KSC  = 0.125f * 1.44269504f;   // scale * log2(e)
    const float THR2 = 8.0f * 1.44269504f;     // defer-max threshold (log2 domain)

    // Q fragments (loop-invariant), straight from global
    const bf16* qrow = Q + qkbase + (size_t)(q0 + wv * 16 + l15) * HD;
    const s8v qf0 = *(const s8v*)(qrow + quad * 8);
    const s8v qf1 = *(const s8v*)(qrow + 32 + quad * 8);

    // staging geometry: lane -> row srow = t>>2 (0..63), 32B = chunks c2, c2+1
    const int srow = t >> 2;
    const int swr  = srow & 7;
    const int c2   = (t & 3) * 2;              // first 16B chunk (0,2,4,6)
    const int ch0  = c2 ^ swr, ch1 = (c2 + 1) ^ swr;   // swizzled LDS chunks

    uint4 kr0, kr1, vr0, vr1; int mr = 1;
    auto LOADT = [&](int kt2) {
        const int kk = kt2 * 64;
        const uint4* kp = (const uint4*)(K  + qkbase + (size_t)(kk + srow) * HD + c2 * 8);
        const uint4* vp = (const uint4*)(Vt + vtbase + (size_t)srow * S_LEN + kk + c2 * 8);
        kr0 = kp[0]; kr1 = kp[1];
        vr0 = vp[0]; vr1 = vp[1];
        if (t < 64) mr = mask[b * S_LEN + kk + t];
    };
    auto STAGE = [&]() {
        *(uint4*)&Ks[srow][ch0 * 8]  = kr0;
        *(uint4*)&Ks[srow][ch1 * 8]  = kr1;
        *(uint4*)&Vts[srow][ch0 * 8] = vr0;
        *(uint4*)&Vts[srow][ch1 * 8] = vr1;
        if (t < 64) mb[t] = mr ? 0.f : -1e30f;
    };

    LOADT(0);

    float mprev = -1e30f, lsum = 0.f;   // per-lane state for q = l15 (lsum partial)
    f4v oacc[4] = {};

    for (int kt = 0; kt < NT; ++kt) {
        __syncthreads();                       // prev-iter LDS reads done
        STAGE();
        __syncthreads();
        if (kt + 1 < NT) LOADT(kt + 1);        // overlap with compute below

        // ---- S^T tiles: rows = k-local, cols = q (swizzled reads) ----
        f4v st[4];
        __builtin_amdgcn_s_setprio(1);
        #pragma unroll
        for (int c = 0; c < 4; ++c) {
            const char* kr = (const char*)&Ks[c * 16 + l15][0];
            s8v kf0 = *(const s8v*)(kr + ((quad ^ sw) << 4));
            s8v kf1 = *(const s8v*)(kr + (((4 + quad) ^ sw) << 4));
            f4v z = {0.f, 0.f, 0.f, 0.f};
            z = __builtin_amdgcn_mfma_f32_16x16x32_bf16(kf0, qf0, z, 0, 0, 0);
            z = __builtin_amdgcn_mfma_f32_16x16x32_bf16(kf1, qf1, z, 0, 0, 0);
            st[c] = z;
        }
        __builtin_amdgcn_s_setprio(0);

        // ---- scale + mask bias (log2 domain, vector FMA); running max ----
        float mt = -1e30f;
        #pragma unroll
        for (int c = 0; c < 4; ++c) {
            const f4v m4 = *(const f4v*)&mb[c * 16 + quad * 4];
            st[c] = st[c] * KSC + m4;
            mt = fmaxf(mt, fmaxf(fmaxf(st[c][0], st[c][1]), fmaxf(st[c][2], st[c][3])));
        }
        mt = fmaxf(mt, __shfl_xor(mt, 16, 64));   // cross-quad: full 64-k max
        mt = fmaxf(mt, __shfl_xor(mt, 32, 64));

        // ---- defer-max rescale ----
        float mn = mprev;
        if (!__all(mt <= mprev + THR2)) {
            mn = fmaxf(mprev, mt);
            const float alpha = __builtin_amdgcn_exp2f(mprev - mn);
            mprev = mn;
            float av[4];
            #pragma unroll
            for (int r = 0; r < 4; ++r) av[r] = __shfl(alpha, quad * 4 + r, 64);
            #pragma unroll
            for (int dt = 0; dt < 4; ++dt)
                #pragma unroll
                for (int r = 0; r < 4; ++r) oacc[dt][r] *= av[r];
            lsum *= alpha;
        }

        f4v psv = {0.f, 0.f, 0.f, 0.f};
        #pragma unroll
        for (int c = 0; c < 4; ++c) {
            f4v e = st[c] - mn;
            e[0] = __builtin_amdgcn_exp2f(e[0]);
            e[1] = __builtin_amdgcn_exp2f(e[1]);
            e[2] = __builtin_amdgcn_exp2f(e[2]);
            e[3] = __builtin_amdgcn_exp2f(e[3]);
            st[c] = e;
            psv += e;
        }
        lsum += psv[0] + psv[1] + psv[2] + psv[3];

        // ---- P -> LDS [q][k] per-wave (swizzled b64 writes), read back as A-frag ----
        char* pr = (char*)&Ps[wv][l15][0];
        #pragma unroll
        for (int c = 0; c < 4; ++c) {
            union { bf16 hh[4]; short4 s4; } pk;
            pk.hh[0] = __float2bfloat16(st[c][0]);
            pk.hh[1] = __float2bfloat16(st[c][1]);
            pk.hh[2] = __float2bfloat16(st[c][2]);
            pk.hh[3] = __float2bfloat16(st[c][3]);
            const int wch = (2 * c + (quad >> 1)) ^ sw;
            *(short4*)(pr + (wch << 4) + ((quad & 1) << 3)) = pk.s4;
        }
        s8v pf0 = *(const s8v*)(pr + ((quad ^ sw) << 4));
        s8v pf1 = *(const s8v*)(pr + (((4 + quad) ^ sw) << 4));

        // ---- O += P V ----
        __builtin_amdgcn_s_setprio(1);
        #pragma unroll
        for (int dt = 0; dt < 4; ++dt) {
            const char* vr = (const char*)&Vts[dt * 16 + l15][0];
            s8v vf0 = *(const s8v*)(vr + ((quad ^ sw) << 4));
            s8v vf1 = *(const s8v*)(vr + (((4 + quad) ^ sw) << 4));
            oacc[dt] = __builtin_amdgcn_mfma_f32_16x16x32_bf16(pf0, vf0, oacc[dt], 0, 0, 0);
            oacc[dt] = __builtin_amdgcn_mfma_f32_16x16x32_bf16(pf1, vf1, oacc[dt], 0, 0, 0);
        }
        __builtin_amdgcn_s_setprio(0);
    }

    // ---- epilogue: finish lsum reduction, then O[b][s][h*64+d] ----
    lsum += __shfl_xor(lsum, 16, 64);
    lsum += __shfl_xor(lsum, 32, 64);
    float linv[4];
    #pragma unroll
    for (int r = 0; r < 4; ++r) linv[r] = 1.f / __shfl(lsum, quad * 4 + r, 64);
    #pragma unroll
    for (int dt = 0; dt < 4; ++dt) {
        #pragma unroll
        for (int r = 0; r < 4; ++r) {
            const int s = q0 + wv * 16 + quad * 4 + r;
            const int col = h * 64 + dt * 16 + l15;
            O[((size_t)b * S_LEN + s) * D_MODEL + col] = __float2bfloat16(oacc[dt][r] * linv[r]);
        }
    }
}

extern "C" void kernel_launch(void* const* d_in, const int* in_sizes, int n_in,
                              void* d_out, int out_size, void* d_ws, size_t ws_size,
                              hipStream_t stream) {
    const float* x    = (const float*)d_in[0];
    const int*   mask = (const int*)  d_in[1];
    const float* Wq   = (const float*)d_in[2];
    const float* bq   = (const float*)d_in[3];
    const float* Wk   = (const float*)d_in[4];
    const float* bk   = (const float*)d_in[5];
    const float* Wv   = (const float*)d_in[6];
    const float* bv   = (const float*)d_in[7];
    const float* Wo   = (const float*)d_in[8];
    const float* bo   = (const float*)d_in[9];
    float* out = (float*)d_out;

    char* w = (char*)d_ws;
    bf16* xb  = (bf16*)w; w += (size_t)M_TOTAL * D_MODEL * 2;
    bf16* Wqb = (bf16*)w; w += (size_t)D_MODEL * D_MODEL * 2;
    bf16* Wkb = (bf16*)w; w += (size_t)D_MODEL * D_MODEL * 2;
    bf16* Wvb = (bf16*)w; w += (size_t)D_MODEL * D_MODEL * 2;
    bf16* Wob = (bf16*)w; w += (size_t)D_MODEL * D_MODEL * 2;
    bf16* Qb  = (bf16*)w; w += (size_t)M_TOTAL * D_MODEL * 2;   // [b][h][s][d]
    bf16* Kb  = (bf16*)w; w += (size_t)M_TOTAL * D_MODEL * 2;   // [b][h][s][d]
    bf16* Vtb = (bf16*)w; w += (size_t)M_TOTAL * D_MODEL * 2;   // [b][h][d][s]
    bf16* Ob  = (bf16*)w; w += (size_t)M_TOTAL * D_MODEL * 2;   // [b][s][1024]

    const int nx = M_TOTAL * D_MODEL;
    cvt_bf16x8<<<nx / 2048, 256, 0, stream>>>(x, xb, nx);
    WPtrs wp = { Wq, Wk, Wv, Wo, Wqb, Wkb, Wvb, Wob };
    cvt_w<<<dim3(D_MODEL * D_MODEL / 2048, 4), 256, 0, stream>>>(wp);

    gemm_qkv<<<dim3(8, 32, 3), 256, 0, stream>>>(xb, Wqb, Wkb, Wvb, bq, bk, bv, Qb, Kb, Vtb);

    attn_mfma<<<BATCH * NH * (S_LEN / 64), 256, 0, stream>>>(Qb, Kb, Vtb, mask, Ob);

    gemm_out<<<dim3(8, 64), 256, 0, stream>>>(Ob, Wob, bo, out);
}